// Round 1
// baseline (372.449 us; speedup 1.0000x reference)
//
#include <hip/hip_runtime.h>
#include <cstddef>

#define H   256
#define L   2048
#define B   32
#define V   50257
#define H2  512
#define H4  1024

// output flat offsets (floats)
#define LP_OFF 0
#define HN_OFF (B*V)                 // 1608224
#define CN_OFF (HN_OFF + B*H)        // 1616416
#define AW_OFF (CN_OFF + B*H)        // 1624608

// workspace layout (floats)
#define WS_W     0                   // 256:  w = We^T v
#define WS_XG    256                 // 32*512: [embedded | attn_applied]
#define WS_XL    (WS_XG + B*H2)      // 32*512: [h_new | attn_applied]
#define WS_PART  (WS_XL + B*H2)      // 32*16*256 attn partial sums
#define WS_GATES (WS_PART + B*16*H)  // 32*1024
#define WS_PM    (WS_GATES + B*H4)   // 256 partial max
#define WS_PZ    (WS_PM + 256)       // 256 partial sumexp
#define WS_M     (WS_PZ + 256)       // 32
#define WS_LZ    (WS_M + 32)         // 32

// ---------------------------------------------------------------- prep:
// block 0: w[h] = sum_k v[k] * W_attn[k, H+h]   (We^T v)
// blocks 1..32: gather embedding row into xg[b][0:256]
__global__ void k_prep(const float* __restrict__ W_attn, const float* __restrict__ v,
                       const int* __restrict__ tokens, const float* __restrict__ emb,
                       float* __restrict__ ws) {
    int t = threadIdx.x;
    if (blockIdx.x == 0) {
        float acc = 0.f;
        #pragma unroll 4
        for (int k = 0; k < H; k++) acc += v[k] * W_attn[k * H2 + H + t];
        ws[WS_W + t] = acc;
    } else {
        int b = blockIdx.x - 1;
        int tok = tokens[b];
        ws[WS_XG + b * H2 + t] = emb[(size_t)tok * H + t];
    }
}

// ---------------------------------------------------------------- scores:
// one wave per (b,l): scores[b,l] = enc[b,l,:] . w  -> written into attn_weights slot
__global__ __launch_bounds__(256) void k_scores(const float* __restrict__ enc,
                                                const float* __restrict__ ws,
                                                float* __restrict__ out) {
    int t = threadIdx.x;
    int wave = t >> 6, lane = t & 63;
    int id = blockIdx.x * 4 + wave;           // = b*L + l, 0..65535
    const float4* e4 = (const float4*)(enc + (size_t)id * H);
    const float4* w4 = (const float4*)(ws + WS_W);
    float4 a = e4[lane];
    float4 w = w4[lane];
    float p = a.x * w.x + a.y * w.y + a.z * w.z + a.w * w.w;
    #pragma unroll
    for (int off = 32; off; off >>= 1) p += __shfl_down(p, off);
    if (lane == 0) out[AW_OFF + id] = p;
}

// ---------------------------------------------------------------- softmax over L per b (in place in d_out)
__global__ __launch_bounds__(256) void k_attn_softmax(float* __restrict__ out) {
    int b = blockIdx.x, t = threadIdx.x;
    __shared__ float red[256];
    float* s = out + AW_OFF + (size_t)b * L;
    float vals[8];
    float vmax = -1e30f;
    #pragma unroll
    for (int j = 0; j < 8; j++) { vals[j] = s[t + 256 * j]; vmax = fmaxf(vmax, vals[j]); }
    red[t] = vmax; __syncthreads();
    for (int off = 128; off; off >>= 1) { if (t < off) red[t] = fmaxf(red[t], red[t + off]); __syncthreads(); }
    float m = red[0]; __syncthreads();
    float sum = 0.f;
    #pragma unroll
    for (int j = 0; j < 8; j++) { vals[j] = expf(vals[j] - m); sum += vals[j]; }
    red[t] = sum; __syncthreads();
    for (int off = 128; off; off >>= 1) { if (t < off) red[t] += red[t + off]; __syncthreads(); }
    float inv = 1.f / red[0];
    #pragma unroll
    for (int j = 0; j < 8; j++) s[t + 256 * j] = vals[j] * inv;
}

// ---------------------------------------------------------------- attn_applied partials:
// block = (b, chunk of 128 l's); thread = h; partial[b,chunk,h] = sum_l w[b,l]*enc[b,l,h]
__global__ __launch_bounds__(256) void k_attn_partial(const float* __restrict__ enc,
                                                      const float* __restrict__ out,
                                                      float* __restrict__ ws) {
    int bid = blockIdx.x;                 // b*16 + chunk
    int b = bid >> 4, chunk = bid & 15;
    int t = threadIdx.x;
    __shared__ float wgt[128];
    if (t < 128) wgt[t] = out[AW_OFF + (size_t)b * L + chunk * 128 + t];
    __syncthreads();
    const float* e = enc + ((size_t)b * L + chunk * 128) * H + t;
    float acc = 0.f;
    #pragma unroll 4
    for (int l = 0; l < 128; l++) acc += wgt[l] * e[(size_t)l * H];
    ws[WS_PART + (size_t)bid * H + t] = acc;
}

__global__ __launch_bounds__(256) void k_attn_reduce(float* __restrict__ ws) {
    int b = blockIdx.x, t = threadIdx.x;
    float acc = 0.f;
    #pragma unroll
    for (int c = 0; c < 16; c++) acc += ws[WS_PART + (size_t)(b * 16 + c) * H + t];
    ws[WS_XG + b * H2 + H + t] = acc;
    ws[WS_XL + b * H2 + H + t] = acc;
}

// ---------------------------------------------------------------- LSTM gates:
// one wave per (b, j): gates = x @ W_ih^T + b_ih + h @ W_hh^T + b_hh
__global__ __launch_bounds__(256) void k_gates(const float* __restrict__ W_ih, const float* __restrict__ b_ih,
                                               const float* __restrict__ W_hh, const float* __restrict__ b_hh,
                                               const float* __restrict__ hidden, float* __restrict__ ws) {
    int t = threadIdx.x;
    int wave = t >> 6, lane = t & 63;
    int o = blockIdx.x * 4 + wave;        // b*1024 + j
    int b = o >> 10, j = o & 1023;
    const float4* wi = (const float4*)(W_ih + (size_t)j * H2);
    const float4* xg = (const float4*)(ws + WS_XG + (size_t)b * H2);
    float4 a0 = wi[lane * 2], a1 = wi[lane * 2 + 1];
    float4 x0 = xg[lane * 2], x1 = xg[lane * 2 + 1];
    float p = a0.x * x0.x + a0.y * x0.y + a0.z * x0.z + a0.w * x0.w
            + a1.x * x1.x + a1.y * x1.y + a1.z * x1.z + a1.w * x1.w;
    const float4* wh = (const float4*)(W_hh + (size_t)j * H);
    const float4* hp = (const float4*)(hidden + (size_t)b * H);
    float4 a2 = wh[lane], x2 = hp[lane];
    p += a2.x * x2.x + a2.y * x2.y + a2.z * x2.z + a2.w * x2.w;
    #pragma unroll
    for (int off = 32; off; off >>= 1) p += __shfl_down(p, off);
    if (lane == 0) ws[WS_GATES + o] = p + b_ih[j] + b_hh[j];
}

// ---------------------------------------------------------------- LSTM cell pointwise
__global__ __launch_bounds__(256) void k_lstm(const float* __restrict__ cell,
                                              float* __restrict__ ws, float* __restrict__ out) {
    int b = blockIdx.x, t = threadIdx.x;
    const float* g = ws + WS_GATES + (size_t)b * H4;
    float ig = g[t], fg = g[H + t], gg = g[2 * H + t], og = g[3 * H + t];
    float c = cell[(size_t)b * H + t];
    float si = 1.f / (1.f + expf(-ig));
    float sf = 1.f / (1.f + expf(-fg));
    float so = 1.f / (1.f + expf(-og));
    float cn = sf * c + si * tanhf(gg);
    float hn = so * tanhf(cn);
    out[HN_OFF + b * H + t] = hn;
    out[CN_OFF + b * H + t] = cn;
    ws[WS_XL + b * H2 + t] = hn;
}

// ---------------------------------------------------------------- logits:
// logits[b,r] = xl[b,:] . W_out[r,:] + b_out[r], written into d_out[LP..]
// block: 128 rows x 32 b; thread: 2 rows x 8 b; K panels of 32 staged in LDS.
__global__ __launch_bounds__(256) void k_logits(const float* __restrict__ W_out,
                                                const float* __restrict__ b_out,
                                                const float* __restrict__ ws,
                                                float* __restrict__ out) {
    __shared__ float Wp[128 * 36];   // stride 36 floats (9 quads): quad-bank = (9r+c)%8 -> conflict-light
    __shared__ float Xp[32 * 36];
    int t = threadIdx.x;
    int r_base = blockIdx.x * 128;
    int m_group = t & 3;              // covers b = m_group*8 .. +7
    int r_group = t >> 2;             // 0..63; rows r_group and r_group+64
    float acc[2][8];
    #pragma unroll
    for (int ri = 0; ri < 2; ri++)
        #pragma unroll
        for (int mi = 0; mi < 8; mi++) acc[ri][mi] = 0.f;

    const float* xl = ws + WS_XL;
    for (int kp = 0; kp < 16; kp++) {
        int k0 = kp * 32;
        __syncthreads();
        // stage W panel: 128 rows x 32 k
        #pragma unroll
        for (int it = 0; it < 4; it++) {
            int idx = t + 256 * it;           // float4 index 0..1023
            int rr = idx >> 3;
            int kk = (idx & 7) * 4;
            int r = r_base + rr;
            float4 val = make_float4(0.f, 0.f, 0.f, 0.f);
            if (r < V) val = *(const float4*)(W_out + (size_t)r * H2 + k0 + kk);
            *(float4*)&Wp[rr * 36 + kk] = val;
        }
        // stage X panel: 32 b x 32 k
        {
            int bb = t >> 3;
            int kk = (t & 7) * 4;
            *(float4*)&Xp[bb * 36 + kk] = *(const float4*)(xl + (size_t)bb * H2 + k0 + kk);
        }
        __syncthreads();
        #pragma unroll
        for (int kk = 0; kk < 32; kk += 4) {
            float4 x4[8];
            #pragma unroll
            for (int mi = 0; mi < 8; mi++) x4[mi] = *(float4*)&Xp[(m_group * 8 + mi) * 36 + kk];
            #pragma unroll
            for (int ri = 0; ri < 2; ri++) {
                float4 w4 = *(float4*)&Wp[(r_group + 64 * ri) * 36 + kk];
                #pragma unroll
                for (int mi = 0; mi < 8; mi++) {
                    acc[ri][mi] += w4.x * x4[mi].x + w4.y * x4[mi].y + w4.z * x4[mi].z + w4.w * x4[mi].w;
                }
            }
        }
    }
    #pragma unroll
    for (int ri = 0; ri < 2; ri++) {
        int r = r_base + r_group + 64 * ri;
        if (r < V) {
            float bo = b_out[r];
            #pragma unroll
            for (int mi = 0; mi < 8; mi++) {
                int b = m_group * 8 + mi;
                out[(size_t)b * V + r] = acc[ri][mi] + bo;
            }
        }
    }
}

// ---------------------------------------------------------------- log_softmax over V per b (3 stages)
#define CHNK 6283  // ceil(V/8)
__global__ __launch_bounds__(256) void k_lsm_part(const float* __restrict__ out, float* __restrict__ ws) {
    int bid = blockIdx.x;            // b*8 + c
    int b = bid >> 3, c = bid & 7;
    int t = threadIdx.x;
    int start = c * CHNK;
    int end = min(V, start + CHNK);
    const float* lg = out + (size_t)b * V;
    __shared__ float red[256];
    float vmax = -1e30f;
    for (int i = start + t; i < end; i += 256) vmax = fmaxf(vmax, lg[i]);
    red[t] = vmax; __syncthreads();
    for (int off = 128; off; off >>= 1) { if (t < off) red[t] = fmaxf(red[t], red[t + off]); __syncthreads(); }
    float m = red[0]; __syncthreads();
    float s = 0.f;
    for (int i = start + t; i < end; i += 256) s += expf(lg[i] - m);
    red[t] = s; __syncthreads();
    for (int off = 128; off; off >>= 1) { if (t < off) red[t] += red[t + off]; __syncthreads(); }
    if (t == 0) { ws[WS_PM + bid] = m; ws[WS_PZ + bid] = red[0]; }
}

__global__ void k_lsm_comb(float* __restrict__ ws) {
    int t = threadIdx.x;
    if (t < B) {
        float m = -1e30f;
        #pragma unroll
        for (int c = 0; c < 8; c++) m = fmaxf(m, ws[WS_PM + t * 8 + c]);
        float z = 0.f;
        #pragma unroll
        for (int c = 0; c < 8; c++) z += ws[WS_PZ + t * 8 + c] * expf(ws[WS_PM + t * 8 + c] - m);
        ws[WS_M + t] = m;
        ws[WS_LZ + t] = logf(z);
    }
}

__global__ __launch_bounds__(256) void k_lsm_final(const float* __restrict__ ws, float* __restrict__ out) {
    int b = blockIdx.y;
    int r = blockIdx.x * 256 + threadIdx.x;
    if (r < V) {
        size_t i = (size_t)b * V + r;
        out[i] = out[i] - ws[WS_M + b] - ws[WS_LZ + b];
    }
}

extern "C" void kernel_launch(void* const* d_in, const int* in_sizes, int n_in,
                              void* d_out, int out_size, void* d_ws, size_t ws_size,
                              hipStream_t stream) {
    const int*   tokens = (const int*)d_in[0];
    const float* hidden = (const float*)d_in[1];
    const float* cell   = (const float*)d_in[2];
    const float* enc    = (const float*)d_in[3];
    const float* emb    = (const float*)d_in[4];
    const float* W_attn = (const float*)d_in[5];
    const float* v      = (const float*)d_in[7];
    const float* W_ih   = (const float*)d_in[8];
    const float* b_ih   = (const float*)d_in[9];
    const float* W_hh   = (const float*)d_in[10];
    const float* b_hh   = (const float*)d_in[11];
    const float* W_out  = (const float*)d_in[12];
    const float* b_out  = (const float*)d_in[13];
    float* out = (float*)d_out;
    float* ws  = (float*)d_ws;

    k_prep<<<1 + B, 256, 0, stream>>>(W_attn, v, tokens, emb, ws);
    k_scores<<<(B * L) / 4, 256, 0, stream>>>(enc, ws, out);
    k_attn_softmax<<<B, 256, 0, stream>>>(out);
    k_attn_partial<<<B * 16, 256, 0, stream>>>(enc, out, ws);
    k_attn_reduce<<<B, 256, 0, stream>>>(ws);
    k_gates<<<(B * H4) / 4, 256, 0, stream>>>(W_ih, b_ih, W_hh, b_hh, hidden, ws);
    k_lstm<<<B, 256, 0, stream>>>(cell, ws, out);
    k_logits<<<(V + 127) / 128, 256, 0, stream>>>(W_out, b_out, ws, out);
    k_lsm_part<<<B * 8, 256, 0, stream>>>(out, ws);
    k_lsm_comb<<<1, 64, 0, stream>>>(ws);
    k_lsm_final<<<dim3((V + 255) / 256, B), 256, 0, stream>>>(ws, out);
}

// Round 2
// 296.523 us; speedup vs baseline: 1.2561x; 1.2561x over previous
//
#include <hip/hip_runtime.h>
#include <cstddef>

#define H   256
#define L   2048
#define B   32
#define V   50257
#define H2  512
#define H4  1024

// output flat offsets (floats)
#define LP_OFF 0
#define HN_OFF (B*V)                 // 1608224
#define CN_OFF (HN_OFF + B*H)        // 1616416
#define AW_OFF (CN_OFF + B*H)        // 1624608

// workspace layout (floats)
#define WS_W     0                   // 256:  w = We^T v
#define WS_XG    256                 // 32*512: [embedded | attn_applied]
#define WS_XL    (WS_XG + B*H2)      // 32*512: [h_new | attn_applied]
#define WS_PART  (WS_XL + B*H2)      // 32*16*256 attn partial sums (dead after k_attn_reduce)
#define WS_PM    WS_PART             // overlay: 32*400 per-(b,block) max
#define WS_PZ    (WS_PM + 12800)     // overlay: 32*400 per-(b,block) sumexp
#define WS_GATES (WS_PART + B*16*H)  // 32*1024
#define WS_M     (WS_GATES + B*H4)   // 32
#define WS_LZ    (WS_M + 32)         // 32

#define NBLK_LOG 393                 // ceil(V/128)

typedef __attribute__((ext_vector_type(8))) short bf16x8;
typedef __attribute__((ext_vector_type(4))) float f32x4;

__device__ inline unsigned short f2bf(float f) {
    unsigned u = __builtin_bit_cast(unsigned, f);
    u += 0x7FFFu + ((u >> 16) & 1u);          // RNE to bf16
    return (unsigned short)(u >> 16);
}

// ---------------------------------------------------------------- prep:
// block 0 (1024 thr): w[h] = sum_k v[k] * W_attn[k, H+h], 4-way k-split
// blocks 1..32 (t<256): gather embedding row into xg[b][0:256]
__global__ __launch_bounds__(1024) void k_prep(const float* __restrict__ W_attn, const float* __restrict__ v,
                                               const int* __restrict__ tokens, const float* __restrict__ emb,
                                               float* __restrict__ ws) {
    int t = threadIdx.x;
    if (blockIdx.x == 0) {
        __shared__ float wred[4 * 256];
        int kq = t >> 8;          // 0..3
        int h  = t & 255;
        const float* base = W_attn + H + h;
        float acc = 0.f;
        #pragma unroll 8
        for (int k = kq * 64; k < kq * 64 + 64; k++) acc += v[k] * base[(size_t)k * H2];
        wred[kq * 256 + h] = acc;
        __syncthreads();
        if (t < 256) {
            ws[WS_W + t] = wred[t] + wred[256 + t] + wred[512 + t] + wred[768 + t];
        }
    } else if (t < 256) {
        int b = blockIdx.x - 1;
        int tok = tokens[b];
        ws[WS_XG + b * H2 + t] = emb[(size_t)tok * H + t];
    }
}

// ---------------------------------------------------------------- scores:
// one wave per (b,l): scores[b,l] = enc[b,l,:] . w  -> written into attn_weights slot
__global__ __launch_bounds__(256) void k_scores(const float* __restrict__ enc,
                                                const float* __restrict__ ws,
                                                float* __restrict__ out) {
    int t = threadIdx.x;
    int wave = t >> 6, lane = t & 63;
    int id = blockIdx.x * 4 + wave;           // = b*L + l, 0..65535
    const float4* e4 = (const float4*)(enc + (size_t)id * H);
    const float4* w4 = (const float4*)(ws + WS_W);
    float4 a = e4[lane];
    float4 w = w4[lane];
    float p = a.x * w.x + a.y * w.y + a.z * w.z + a.w * w.w;
    #pragma unroll
    for (int off = 32; off; off >>= 1) p += __shfl_down(p, off);
    if (lane == 0) out[AW_OFF + id] = p;
}

// ---------------------------------------------------------------- softmax over L per b (in place in d_out)
__global__ __launch_bounds__(256) void k_attn_softmax(float* __restrict__ out) {
    int b = blockIdx.x, t = threadIdx.x;
    __shared__ float red[256];
    float* s = out + AW_OFF + (size_t)b * L;
    float vals[8];
    float vmax = -1e30f;
    #pragma unroll
    for (int j = 0; j < 8; j++) { vals[j] = s[t + 256 * j]; vmax = fmaxf(vmax, vals[j]); }
    red[t] = vmax; __syncthreads();
    for (int off = 128; off; off >>= 1) { if (t < off) red[t] = fmaxf(red[t], red[t + off]); __syncthreads(); }
    float m = red[0]; __syncthreads();
    float sum = 0.f;
    #pragma unroll
    for (int j = 0; j < 8; j++) { vals[j] = expf(vals[j] - m); sum += vals[j]; }
    red[t] = sum; __syncthreads();
    for (int off = 128; off; off >>= 1) { if (t < off) red[t] += red[t + off]; __syncthreads(); }
    float inv = 1.f / red[0];
    #pragma unroll
    for (int j = 0; j < 8; j++) s[t + 256 * j] = vals[j] * inv;
}

// ---------------------------------------------------------------- attn_applied partials:
// block = (b, chunk of 128 l's); thread = h; partial[b,chunk,h] = sum_l w[b,l]*enc[b,l,h]
__global__ __launch_bounds__(256) void k_attn_partial(const float* __restrict__ enc,
                                                      const float* __restrict__ out,
                                                      float* __restrict__ ws) {
    int bid = blockIdx.x;                 // b*16 + chunk
    int b = bid >> 4, chunk = bid & 15;
    int t = threadIdx.x;
    __shared__ float wgt[128];
    if (t < 128) wgt[t] = out[AW_OFF + (size_t)b * L + chunk * 128 + t];
    __syncthreads();
    const float* e = enc + ((size_t)b * L + chunk * 128) * H + t;
    float acc = 0.f;
    #pragma unroll 4
    for (int l = 0; l < 128; l++) acc += wgt[l] * e[(size_t)l * H];
    ws[WS_PART + (size_t)bid * H + t] = acc;
}

__global__ __launch_bounds__(256) void k_attn_reduce(float* __restrict__ ws) {
    int b = blockIdx.x, t = threadIdx.x;
    float acc = 0.f;
    #pragma unroll
    for (int c = 0; c < 16; c++) acc += ws[WS_PART + (size_t)(b * 16 + c) * H + t];
    ws[WS_XG + b * H2 + H + t] = acc;
    ws[WS_XL + b * H2 + H + t] = acc;
}

// ---------------------------------------------------------------- LSTM gates:
// one wave per (b, j): gates = x @ W_ih^T + b_ih + h @ W_hh^T + b_hh
__global__ __launch_bounds__(256) void k_gates(const float* __restrict__ W_ih, const float* __restrict__ b_ih,
                                               const float* __restrict__ W_hh, const float* __restrict__ b_hh,
                                               const float* __restrict__ hidden, float* __restrict__ ws) {
    int t = threadIdx.x;
    int wave = t >> 6, lane = t & 63;
    int o = blockIdx.x * 4 + wave;        // b*1024 + j
    int b = o >> 10, j = o & 1023;
    const float4* wi = (const float4*)(W_ih + (size_t)j * H2);
    const float4* xg = (const float4*)(ws + WS_XG + (size_t)b * H2);
    float4 a0 = wi[lane * 2], a1 = wi[lane * 2 + 1];
    float4 x0 = xg[lane * 2], x1 = xg[lane * 2 + 1];
    float p = a0.x * x0.x + a0.y * x0.y + a0.z * x0.z + a0.w * x0.w
            + a1.x * x1.x + a1.y * x1.y + a1.z * x1.z + a1.w * x1.w;
    const float4* wh = (const float4*)(W_hh + (size_t)j * H);
    const float4* hp = (const float4*)(hidden + (size_t)b * H);
    float4 a2 = wh[lane], x2 = hp[lane];
    p += a2.x * x2.x + a2.y * x2.y + a2.z * x2.z + a2.w * x2.w;
    #pragma unroll
    for (int off = 32; off; off >>= 1) p += __shfl_down(p, off);
    if (lane == 0) ws[WS_GATES + o] = p + b_ih[j] + b_hh[j];
}

// ---------------------------------------------------------------- LSTM cell pointwise
__global__ __launch_bounds__(256) void k_lstm(const float* __restrict__ cell,
                                              float* __restrict__ ws, float* __restrict__ out) {
    int b = blockIdx.x, t = threadIdx.x;
    const float* g = ws + WS_GATES + (size_t)b * H4;
    float ig = g[t], fg = g[H + t], gg = g[2 * H + t], og = g[3 * H + t];
    float c = cell[(size_t)b * H + t];
    float si = 1.f / (1.f + expf(-ig));
    float sf = 1.f / (1.f + expf(-fg));
    float so = 1.f / (1.f + expf(-og));
    float cn = sf * c + si * tanhf(gg);
    float hn = so * tanhf(cn);
    out[HN_OFF + b * H + t] = hn;
    out[CN_OFF + b * H + t] = cn;
    ws[WS_XL + b * H2 + t] = hn;
}

// ---------------------------------------------------------------- logits (bf16 MFMA):
// C[b,r] = X[b,:].W_out[r,:] + b_out[r].  Block = 128 rows; wave = 32 rows (2 strips
// of 16) x 32 batches (2 n-tiles of 16).  W_out loaded f32->bf16 in-register;
// X staged in LDS as bf16 (pad +8 -> 2-way conflicts only).  Epilogue computes
// per-block log-softmax partials (max, sumexp) -> ws.
__global__ __launch_bounds__(256) void k_logits(const float* __restrict__ W_out,
                                                const float* __restrict__ b_out,
                                                float* __restrict__ ws,
                                                float* __restrict__ out) {
    __shared__ unsigned short Xl[32 * 520];   // 33,280 B
    int t = threadIdx.x;
    // stage X = ws[WS_XL] (32x512 f32) -> bf16 LDS
    const float4* xl4 = (const float4*)(ws + WS_XL);
    #pragma unroll
    for (int it = 0; it < 16; it++) {
        int fi = t + 256 * it;                // float4 index over 32x128
        int b = fi >> 7, kq = fi & 127;
        float4 xv = xl4[b * 128 + kq];
        unsigned p0 = (unsigned)f2bf(xv.x) | ((unsigned)f2bf(xv.y) << 16);
        unsigned p1 = (unsigned)f2bf(xv.z) | ((unsigned)f2bf(xv.w) << 16);
        unsigned* dst = (unsigned*)&Xl[b * 520 + kq * 4];
        dst[0] = p0; dst[1] = p1;
    }
    __syncthreads();

    int wave = t >> 6, lane = t & 63, quad = lane >> 4, m = lane & 15;
    int rbase = blockIdx.x * 128 + wave * 32;
    f32x4 zero4 = {0.f, 0.f, 0.f, 0.f};
    f32x4 acc[2][2];
    acc[0][0] = zero4; acc[0][1] = zero4; acc[1][0] = zero4; acc[1][1] = zero4;

    int r0 = rbase + m;          // strip 0 A-row for this lane
    int r1 = rbase + 16 + m;     // strip 1
    bool v0 = r0 < V, v1 = r1 < V;
    const float* wp0 = W_out + (size_t)r0 * H2 + quad * 8;
    const float* wp1 = W_out + (size_t)r1 * H2 + quad * 8;

    for (int kp = 0; kp < 16; kp++) {
        int k0 = kp * 32;
        bf16x8 a0 = {0,0,0,0,0,0,0,0}, a1 = {0,0,0,0,0,0,0,0};
        if (v0) {
            float4 lo = *(const float4*)(wp0 + k0);
            float4 hi = *(const float4*)(wp0 + k0 + 4);
            a0[0]=(short)f2bf(lo.x); a0[1]=(short)f2bf(lo.y); a0[2]=(short)f2bf(lo.z); a0[3]=(short)f2bf(lo.w);
            a0[4]=(short)f2bf(hi.x); a0[5]=(short)f2bf(hi.y); a0[6]=(short)f2bf(hi.z); a0[7]=(short)f2bf(hi.w);
        }
        if (v1) {
            float4 lo = *(const float4*)(wp1 + k0);
            float4 hi = *(const float4*)(wp1 + k0 + 4);
            a1[0]=(short)f2bf(lo.x); a1[1]=(short)f2bf(lo.y); a1[2]=(short)f2bf(lo.z); a1[3]=(short)f2bf(lo.w);
            a1[4]=(short)f2bf(hi.x); a1[5]=(short)f2bf(hi.y); a1[6]=(short)f2bf(hi.z); a1[7]=(short)f2bf(hi.w);
        }
        bf16x8 b0 = *(bf16x8*)&Xl[(size_t)m * 520 + k0 + quad * 8];          // batches 0..15
        bf16x8 b1 = *(bf16x8*)&Xl[(size_t)(16 + m) * 520 + k0 + quad * 8];   // batches 16..31
        acc[0][0] = __builtin_amdgcn_mfma_f32_16x16x32_bf16(a0, b0, acc[0][0], 0, 0, 0);
        acc[0][1] = __builtin_amdgcn_mfma_f32_16x16x32_bf16(a0, b1, acc[0][1], 0, 0, 0);
        acc[1][0] = __builtin_amdgcn_mfma_f32_16x16x32_bf16(a1, b0, acc[1][0], 0, 0, 0);
        acc[1][1] = __builtin_amdgcn_mfma_f32_16x16x32_bf16(a1, b1, acc[1][1], 0, 0, 0);
    }

    // epilogue: bias, store, per-wave softmax partials
    float val[2][2][4];
    #pragma unroll
    for (int s = 0; s < 2; s++) {
        #pragma unroll
        for (int i = 0; i < 4; i++) {
            int rr = rbase + s * 16 + quad * 4 + i;
            float bo = (rr < V) ? b_out[rr] : 0.f;
            #pragma unroll
            for (int nt = 0; nt < 2; nt++) {
                float vv = acc[s][nt][i] + bo;
                if (rr < V) {
                    int bcol = nt * 16 + m;          // D col = lane&15
                    out[(size_t)bcol * V + rr] = vv;
                    val[s][nt][i] = vv;
                } else {
                    val[s][nt][i] = -1e30f;
                }
            }
        }
    }
    float pm[2], pz[2];
    #pragma unroll
    for (int nt = 0; nt < 2; nt++) {
        float mx = -1e30f;
        #pragma unroll
        for (int s = 0; s < 2; s++)
            #pragma unroll
            for (int i = 0; i < 4; i++) mx = fmaxf(mx, val[s][nt][i]);
        float sm = 0.f;
        #pragma unroll
        for (int s = 0; s < 2; s++)
            #pragma unroll
            for (int i = 0; i < 4; i++) sm += __expf(val[s][nt][i] - mx);
        pm[nt] = mx; pz[nt] = sm;
    }
    // combine across the 4 quads (lanes m, m+16, m+32, m+48 share batch col)
    #pragma unroll
    for (int off = 16; off <= 32; off <<= 1) {
        #pragma unroll
        for (int nt = 0; nt < 2; nt++) {
            float om = __shfl_xor(pm[nt], off);
            float oz = __shfl_xor(pz[nt], off);
            float nm = fmaxf(pm[nt], om);
            pz[nt] = pz[nt] * __expf(pm[nt] - nm) + oz * __expf(om - nm);
            pm[nt] = nm;
        }
    }
    __syncthreads();                      // Xl reads done; reuse as float scratch
    float* red = (float*)Xl;
    if (quad == 0) {
        #pragma unroll
        for (int nt = 0; nt < 2; nt++) {
            red[wave * 32 + nt * 16 + m]       = pm[nt];
            red[128 + wave * 32 + nt * 16 + m] = pz[nt];
        }
    }
    __syncthreads();
    if (t < 32) {
        float mf = -1e30f;
        #pragma unroll
        for (int w = 0; w < 4; w++) mf = fmaxf(mf, red[w * 32 + t]);
        float z = 0.f;
        #pragma unroll
        for (int w = 0; w < 4; w++) z += red[128 + w * 32 + t] * __expf(red[w * 32 + t] - mf);
        ws[WS_PM + t * 400 + blockIdx.x] = mf;
        ws[WS_PZ + t * 400 + blockIdx.x] = z;
    }
}

// ---------------------------------------------------------------- combine log-softmax partials
__global__ __launch_bounds__(256) void k_lsm_comb(float* __restrict__ ws) {
    int b = blockIdx.x, t = threadIdx.x;
    float m = -1e30f, z = 0.f;
    for (int i = t; i < NBLK_LOG; i += 256) {
        float mi = ws[WS_PM + b * 400 + i];
        float zi = ws[WS_PZ + b * 400 + i];
        float nm = fmaxf(m, mi);
        z = z * __expf(m - nm) + zi * __expf(mi - nm);
        m = nm;
    }
    __shared__ float rm[256], rz[256];
    rm[t] = m; rz[t] = z; __syncthreads();
    for (int off = 128; off; off >>= 1) {
        if (t < off) {
            float m2 = rm[t + off], z2 = rz[t + off];
            float nm = fmaxf(rm[t], m2);
            rz[t] = rz[t] * __expf(rm[t] - nm) + z2 * __expf(m2 - nm);
            rm[t] = nm;
        }
        __syncthreads();
    }
    if (t == 0) { ws[WS_M + b] = rm[0]; ws[WS_LZ + b] = logf(rz[0]); }
}

__global__ __launch_bounds__(256) void k_lsm_final(const float* __restrict__ ws, float* __restrict__ out) {
    int b = blockIdx.y;
    int r = blockIdx.x * 256 + threadIdx.x;
    if (r < V) {
        size_t i = (size_t)b * V + r;
        out[i] = out[i] - ws[WS_M + b] - ws[WS_LZ + b];
    }
}

extern "C" void kernel_launch(void* const* d_in, const int* in_sizes, int n_in,
                              void* d_out, int out_size, void* d_ws, size_t ws_size,
                              hipStream_t stream) {
    const int*   tokens = (const int*)d_in[0];
    const float* hidden = (const float*)d_in[1];
    const float* cell   = (const float*)d_in[2];
    const float* enc    = (const float*)d_in[3];
    const float* emb    = (const float*)d_in[4];
    const float* W_attn = (const float*)d_in[5];
    const float* v      = (const float*)d_in[7];
    const float* W_ih   = (const float*)d_in[8];
    const float* b_ih   = (const float*)d_in[9];
    const float* W_hh   = (const float*)d_in[10];
    const float* b_hh   = (const float*)d_in[11];
    const float* W_out  = (const float*)d_in[12];
    const float* b_out  = (const float*)d_in[13];
    float* out = (float*)d_out;
    float* ws  = (float*)d_ws;

    k_prep<<<1 + B, 1024, 0, stream>>>(W_attn, v, tokens, emb, ws);
    k_scores<<<(B * L) / 4, 256, 0, stream>>>(enc, ws, out);
    k_attn_softmax<<<B, 256, 0, stream>>>(out);
    k_attn_partial<<<B * 16, 256, 0, stream>>>(enc, out, ws);
    k_attn_reduce<<<B, 256, 0, stream>>>(ws);
    k_gates<<<(B * H4) / 4, 256, 0, stream>>>(W_ih, b_ih, W_hh, b_hh, hidden, ws);
    k_lstm<<<B, 256, 0, stream>>>(cell, ws, out);
    k_logits<<<NBLK_LOG, 256, 0, stream>>>(W_out, b_out, ws, out);
    k_lsm_comb<<<B, 256, 0, stream>>>(ws);
    k_lsm_final<<<dim3((V + 255) / 256, B), 256, 0, stream>>>(ws, out);
}